// Round 3
// baseline (422.797 us; speedup 1.0000x reference)
//
#include <hip/hip_runtime.h>
#include <math.h>

// Problem constants (from reference)
#define T_LEN   1024
#define N_INPUT 1024
#define H_DIM   128
#define BATCH   2

// Output layout (PLANES hypothesis): d_out is 2 * T*B*H*H float32:
//   plane 0 = real parts of out[t,b,j,k], row-major (t,b,j,k)
//   plane 1 = imag parts, same order, offset PLANE = T*B*H*H floats.
#define PLANE ((size_t)T_LEN * BATCH * H_DIM * H_DIM)   // 33,554,432

// ---------------------------------------------------------------------------
// Fully fused kernel: no d_ws usage (ws_size on this harness is < 2.1 MB).
// One block per (b,j): stages b_bar[j,:] in LDS, computes the bu row for
// (b,j), then runs the k-parallel scan with coalesced plane stores.
// ---------------------------------------------------------------------------
__global__ __launch_bounds__(128) void fused_kernel(const float* __restrict__ u,
                                                    const float* __restrict__ delta_p,
                                                    const float* __restrict__ lre,
                                                    const float* __restrict__ lim,
                                                    const float* __restrict__ b_re,
                                                    const float* __restrict__ b_im,
                                                    float* __restrict__ out,
                                                    size_t n_float) {
    __shared__ float2 sb[N_INPUT];      // b_bar[j,:] (8 KB)
    __shared__ float2 sbu[T_LEN];       // bu row (8 KB)
    __shared__ float2 sc[H_DIM];        // c[h]

    int blk = blockIdx.x;               // b*128 + j
    int b   = blk >> 7;
    int j   = blk & 127;
    int tid = threadIdx.x;

    // --- discretization constants: lane tid computes h=tid ---
    float delta = delta_p[0];
    float ar = lre[tid];
    float ai = lim[tid];
    float e = expf(ar * delta);
    float s, co;
    sincosf(ai * delta, &s, &co);
    float lbr = e * co;    // lambda_bar for k = tid (used directly in scan)
    float lbi = e * s;
    {
        // c = (lambda_bar - 1) / lambda  (complex divide)
        float nr = lbr - 1.0f;
        float ni = lbi;
        float d  = ar * ar + ai * ai;
        sc[tid] = make_float2((nr * ar + ni * ai) / d, (ni * ar - nr * ai) / d);
    }
    __syncthreads();
    float cre = sc[j].x;
    float cim = sc[j].y;

    // --- stage b_bar[j,:] = c[j] * (b_re[j,:] + i b_im[j,:]) into LDS ---
    {
        const float4* br4 = (const float4*)(b_re + (size_t)j * N_INPUT);
        const float4* bi4 = (const float4*)(b_im + (size_t)j * N_INPUT);
#pragma unroll
        for (int r = 0; r < 2; ++r) {
            int i4 = r * 128 + tid;           // 256 float4 covers 1024 floats
            float4 brv = br4[i4];
            float4 biv = bi4[i4];
            sb[i4 * 4 + 0] = make_float2(cre * brv.x - cim * biv.x, cre * biv.x + cim * brv.x);
            sb[i4 * 4 + 1] = make_float2(cre * brv.y - cim * biv.y, cre * biv.y + cim * brv.y);
            sb[i4 * 4 + 2] = make_float2(cre * brv.z - cim * biv.z, cre * biv.z + cim * brv.z);
            sb[i4 * 4 + 3] = make_float2(cre * brv.w - cim * biv.w, cre * biv.w + cim * brv.w);
        }
    }
    __syncthreads();

    // --- compute bu[t] for t = r*128 + tid, r = 0..7 ---
    const float4* sbf4 = (const float4*)sb;   // pairs: (re0,im0,re1,im1)
#pragma unroll 1
    for (int r = 0; r < 8; ++r) {
        int t = r * 128 + tid;
        const float4* u4 = (const float4*)(u + ((size_t)b * T_LEN + t) * N_INPUT);
        float accr = 0.0f, acci = 0.0f;
        for (int i4 = 0; i4 < N_INPUT / 4; ++i4) {
            float4 uv  = u4[i4];
            float4 s01 = sbf4[2 * i4];
            float4 s23 = sbf4[2 * i4 + 1];
            accr += uv.x * s01.x + uv.y * s01.z + uv.z * s23.x + uv.w * s23.z;
            acci += uv.x * s01.y + uv.y * s01.w + uv.z * s23.y + uv.w * s23.w;
        }
        sbu[t] = make_float2(accr, acci);
    }
    __syncthreads();

    // --- scan over t; plane-separated coalesced float stores ---
    int k = tid;
    size_t base = ((size_t)b * H_DIM + j) * H_DIM + k;     // within-plane index at t=0
    const size_t t_stride = (size_t)BATCH * H_DIM * H_DIM; // 32768 per t

    float xr = 0.0f, xi = 0.0f;
    for (int t = 0; t < T_LEN; ++t) {
        float2 bu = sbu[t];
        float nxr = lbr * xr - lbi * xi + bu.x;
        float nxi = lbr * xi + lbi * xr + bu.y;
        xr = nxr;
        xi = nxi;
        size_t idx = base + (size_t)t * t_stride;     // real-plane float index
        if (idx < n_float) out[idx] = xr;
        size_t idx_im = idx + PLANE;                  // imag-plane float index
        if (idx_im < n_float) out[idx_im] = xi;
    }
}

// ---------------------------------------------------------------------------
extern "C" void kernel_launch(void* const* d_in, const int* in_sizes, int n_in,
                              void* d_out, int out_size, void* d_ws, size_t ws_size,
                              hipStream_t stream) {
    const float* u      = (const float*)d_in[0];
    const float* delta  = (const float*)d_in[1];
    const float* lre    = (const float*)d_in[2];
    const float* lim    = (const float*)d_in[3];
    const float* b_re   = (const float*)d_in[4];
    const float* b_im   = (const float*)d_in[5];
    float* out = (float*)d_out;
    size_t n_float = (size_t)out_size;   // total output floats (2 planes)

    fused_kernel<<<BATCH * H_DIM, 128, 0, stream>>>(u, delta, lre, lim,
                                                    b_re, b_im, out, n_float);
}

// Round 6
// 280.846 us; speedup vs baseline: 1.5054x; 1.5054x over previous
//
#include <hip/hip_runtime.h>
#include <math.h>

// Problem constants (from reference)
#define T_LEN   1024
#define N_INPUT 1024
#define H_DIM   128
#define BATCH   2
#define TC      128          // scan chunk length
#define NC      8            // number of chunks (TC*NC == T_LEN)

// Output layout (verified R3/R5 bisect): d_out holds ONLY the real part:
//   out[t][b][j][k] row-major, 33,554,432 float32 (numpy complex->float32
//   cast drops imag). Imag state is carried internally, never stored.
#define PLANE ((size_t)T_LEN * BATCH * H_DIM * H_DIM)   // 33,554,432
#define TSTRIDE ((size_t)BATCH * H_DIM * H_DIM)         // 32,768 per t

// ---------------------------------------------------------------------------
// Fused kernel, chunked scan. Grid = 256 blocks (one per (b,j)), 1024 threads
// = 8 chunks x 128 k-lanes. No d_ws usage (ws too small on this harness).
// ---------------------------------------------------------------------------
__global__ __launch_bounds__(1024)
void fused_kernel(const float* __restrict__ u,
                  const float* __restrict__ delta_p,
                  const float* __restrict__ lre,
                  const float* __restrict__ lim,
                  const float* __restrict__ b_re,
                  const float* __restrict__ b_im,
                  float* __restrict__ out,
                  size_t n_float) {
    __shared__ float2 sb[N_INPUT];       // b_bar[j,:]            (8 KB)
    __shared__ float2 sbu[T_LEN];        // bu row for (b,j)      (8 KB)
    __shared__ float2 sc[H_DIM];         // c[h]                  (1 KB)
    __shared__ float2 sP[NC][H_DIM];     // chunk partials        (8 KB)
    __shared__ float2 sX[NC][H_DIM];     // chunk start states    (8 KB)

    int blk = blockIdx.x;                // b*128 + j
    int b   = blk >> 7;
    int j   = blk & 127;
    int tid = threadIdx.x;
    int k   = tid & 127;                 // state index (scan lane)
    int c   = tid >> 7;                  // chunk index (0..7)

    // --- discretization constants; every thread derives lambda_bar for its k
    float delta = delta_p[0];
    float ar = lre[k];
    float ai = lim[k];
    float e = expf(ar * delta);
    float s_, co;
    sincosf(ai * delta, &s_, &co);
    float lbr = e * co;
    float lbi = e * s_;
    if (tid < H_DIM) {
        // c[h] = (lambda_bar - 1) / lambda
        float nr = lbr - 1.0f;
        float ni = lbi;
        float d  = ar * ar + ai * ai;
        sc[tid] = make_float2((nr * ar + ni * ai) / d, (ni * ar - nr * ai) / d);
    }
    __syncthreads();
    float cre = sc[j].x;
    float cim = sc[j].y;

    // --- stage b_bar[j,:] = c[j] * (b_re[j,:] + i b_im[j,:]) (1 elem/thread)
    {
        float br = b_re[(size_t)j * N_INPUT + tid];
        float bi = b_im[(size_t)j * N_INPUT + tid];
        sb[tid] = make_float2(cre * br - cim * bi, cre * bi + cim * br);
    }
    __syncthreads();

    // --- bu[t] for t = tid: complex dot(b_bar[j,:], u[b,t,:])
    {
        int t = tid;
        const float4* u4   = (const float4*)(u + ((size_t)b * T_LEN + t) * N_INPUT);
        const float4* sbf4 = (const float4*)sb;   // (re0,im0,re1,im1) pairs
        float accr = 0.0f, acci = 0.0f;
        for (int i4 = 0; i4 < N_INPUT / 4; ++i4) {
            float4 uv  = u4[i4];
            float4 s01 = sbf4[2 * i4];
            float4 s23 = sbf4[2 * i4 + 1];
            accr += uv.x * s01.x + uv.y * s01.z + uv.z * s23.x + uv.w * s23.z;
            acci += uv.x * s01.y + uv.y * s01.w + uv.z * s23.y + uv.w * s23.w;
        }
        sbu[t] = make_float2(accr, acci);
    }
    __syncthreads();

    // --- per-chunk partial: P_c(k) = sum_{s} lambda^{TC-1-s} * bu[c*TC+s]
    {
        float pr = 0.0f, pi = 0.0f;
        int t0 = c * TC;
        for (int s2 = 0; s2 < TC; ++s2) {
            float2 bu = sbu[t0 + s2];            // broadcast across k-lanes
            float nr = lbr * pr - lbi * pi + bu.x;
            float ni = lbr * pi + lbi * pr + bu.y;
            pr = nr; pi = ni;
        }
        sP[c][k] = make_float2(pr, pi);
    }
    __syncthreads();

    // --- chunk-boundary combine (128 threads): x_start(c) via G = lambda^TC
    if (tid < H_DIM) {
        float gr = lbr, gi = lbi;
#pragma unroll
        for (int q = 0; q < 7; ++q) {            // lambda^(2^7) = lambda^128
            float tr = gr * gr - gi * gi;
            float ti = 2.0f * gr * gi;
            gr = tr; gi = ti;
        }
        float xr = 0.0f, xi = 0.0f;
#pragma unroll
        for (int cc = 0; cc < NC; ++cc) {
            sX[cc][tid] = make_float2(xr, xi);   // state BEFORE chunk cc
            float2 p = sP[cc][tid];
            float nr = gr * xr - gi * xi + p.x;
            float ni = gr * xi + gi * xr + p.y;
            xr = nr; xi = ni;
        }
    }
    __syncthreads();

    // --- final scan within chunk; store REAL part only (nontemporal)
    if (PLANE <= n_float) {                      // max idx = PLANE-1
        float2 x0 = sX[c][k];
        float xr = x0.x, xi = x0.y;
        int t0 = c * TC;
        float* outr = out + ((size_t)b * H_DIM + j) * H_DIM + k + (size_t)t0 * TSTRIDE;
        for (int s2 = 0; s2 < TC; ++s2) {
            float2 bu = sbu[t0 + s2];            // broadcast
            float nr = lbr * xr - lbi * xi + bu.x;
            float ni = lbr * xi + lbi * xr + bu.y;
            xr = nr; xi = ni;
            __builtin_nontemporal_store(xr, outr + (size_t)s2 * TSTRIDE);
        }
    }
}

// ---------------------------------------------------------------------------
extern "C" void kernel_launch(void* const* d_in, const int* in_sizes, int n_in,
                              void* d_out, int out_size, void* d_ws, size_t ws_size,
                              hipStream_t stream) {
    const float* u      = (const float*)d_in[0];
    const float* delta  = (const float*)d_in[1];
    const float* lre    = (const float*)d_in[2];
    const float* lim    = (const float*)d_in[3];
    const float* b_re   = (const float*)d_in[4];
    const float* b_im   = (const float*)d_in[5];
    float* out = (float*)d_out;
    size_t n_float = (size_t)out_size;

    fused_kernel<<<BATCH * H_DIM, NC * H_DIM, 0, stream>>>(u, delta, lre, lim,
                                                           b_re, b_im, out, n_float);
}

// Round 7
// 200.480 us; speedup vs baseline: 2.1089x; 1.4009x over previous
//
#include <hip/hip_runtime.h>
#include <math.h>

// Problem constants (from reference)
#define T_LEN   1024
#define N_INPUT 1024
#define H_DIM   128
#define BATCH   2
#define TC      128          // scan chunk length
#define NC      8            // number of chunks (TC*NC == T_LEN)

// Output layout (verified R6): d_out holds ONLY the real part:
//   out[t][b][j][k] row-major, 33,554,432 float32.
#define PLANE   ((size_t)T_LEN * BATCH * H_DIM * H_DIM)  // 33,554,432
#define TSTRIDE ((size_t)BATCH * H_DIM * H_DIM)          // 32,768 per t

// bu stash: parked in out's t in [1008,1024) slots. Cell (b,j,t,comp) lives at
//   (1008 + (t>>6))*TSTRIDE + b*16384 + j*128 + (t&63)*2 + comp
// Block (b,j) of pass 2 reads ONLY its own (b,j) columns, which it alone
// overwrites at the end of its scan -> race-free across the kernel boundary.

// ---------------------------------------------------------------------------
// Pass 1: bu[b][j][t] = c[j] * dot(b_re[j,:]+i*b_im[j,:], u[b,t,:])
// Grid 256 = (b, tg of 8 rows). 1024 threads = (j, c8): 8-way i-split.
// ---------------------------------------------------------------------------
__global__ __launch_bounds__(1024)
void bu_kernel(const float* __restrict__ u,
               const float* __restrict__ delta_p,
               const float* __restrict__ lre,
               const float* __restrict__ lim,
               const float* __restrict__ b_re,
               const float* __restrict__ b_im,
               float* __restrict__ out) {
    __shared__ float su[8][N_INPUT];     // 8 u rows      (32 KB)
    __shared__ float sred[2048];         // bu results    (8 KB)

    int blk = blockIdx.x;                // b*128 + tg
    int b   = blk >> 7;
    int tg  = blk & 127;
    int tid = threadIdx.x;
    int j   = tid >> 3;                  // 0..127
    int c8  = tid & 7;                   // 8-way split of i

    // stage u rows t = tg*8 .. tg*8+7 (coalesced float4)
    const float4* g4 = (const float4*)(u + ((size_t)b * T_LEN + (size_t)tg * 8) * N_INPUT);
    float4* s4 = (float4*)su;
    s4[tid]        = g4[tid];
    s4[tid + 1024] = g4[tid + 1024];
    __syncthreads();

    const float4* br4 = (const float4*)b_re;
    const float4* bi4 = (const float4*)b_im;
    int bbase = j * 256 + c8;            // float4 index of row j, chunk c8

    float accr[8], acci[8];
#pragma unroll
    for (int t = 0; t < 8; ++t) { accr[t] = 0.0f; acci[t] = 0.0f; }

    for (int ii = 0; ii < 32; ++ii) {
        float4 br = br4[bbase + ii * 8];
        float4 bi = bi4[bbase + ii * 8];
        int w = (ii * 8 + c8) * 4;       // float offset in a row
#pragma unroll
        for (int t = 0; t < 8; ++t) {
            float4 uv = *(const float4*)&su[t][w];   // 8-lane broadcast, no conflict
            accr[t] += br.x * uv.x + br.y * uv.y + br.z * uv.z + br.w * uv.w;
            acci[t] += bi.x * uv.x + bi.y * uv.y + bi.z * uv.z + bi.w * uv.w;
        }
    }

    // c[j] = (lambda_bar - 1) / lambda
    float delta = delta_p[0];
    float ar = lre[j], ai = lim[j];
    float e = expf(ar * delta);
    float s_, co;
    sincosf(ai * delta, &s_, &co);
    float lbr = e * co, lbi = e * s_;
    float nr = lbr - 1.0f, ni = lbi, dd = ar * ar + ai * ai;
    float cr = (nr * ar + ni * ai) / dd, ci = (ni * ar - nr * ai) / dd;

#pragma unroll
    for (int t = 0; t < 8; ++t) {
        float r = accr[t], i = acci[t];
        r += __shfl_xor(r, 1);  i += __shfl_xor(i, 1);
        r += __shfl_xor(r, 2);  i += __shfl_xor(i, 2);
        r += __shfl_xor(r, 4);  i += __shfl_xor(i, 4);
        if (c8 == 0) {
            sred[j * 16 + t * 2]     = cr * r - ci * i;
            sred[j * 16 + t * 2 + 1] = cr * i + ci * r;
        }
    }
    __syncthreads();

    // write stash: block's region = rows (1008+tg>>3), k in (tg&7)*16+[0,16)
    size_t wb = (size_t)(1008 + (tg >> 3)) * TSTRIDE + (size_t)b * 16384 + (size_t)(tg & 7) * 16;
#pragma unroll
    for (int r = 0; r < 2; ++r) {
        int e2 = tid + r * 1024;         // element [j=e2>>4][m=e2&15]
        out[wb + (size_t)(e2 >> 4) * 128 + (e2 & 15)] = sred[e2];
    }
}

// ---------------------------------------------------------------------------
// Pass 2: chunked scan (R6 structure minus dot phase).
// Grid 256 = (b,j), 1024 threads = 8 chunks x 128 k-lanes.
// ---------------------------------------------------------------------------
__global__ __launch_bounds__(1024)
void scan_kernel(const float* __restrict__ delta_p,
                 const float* __restrict__ lre,
                 const float* __restrict__ lim,
                 float* out) {
    __shared__ float2 sbu[T_LEN];        // bu row      (8 KB)
    __shared__ float2 sP[NC][H_DIM];     // partials    (8 KB)
    __shared__ float2 sX[NC][H_DIM];     // starts      (8 KB)

    int blk = blockIdx.x;                // b*128 + j
    int b   = blk >> 7;
    int j   = blk & 127;
    int tid = threadIdx.x;
    int k   = tid & 127;
    int c   = tid >> 7;

    // load this (b,j)'s bu row from the stash (coalesced float2)
    {
        int s = tid >> 6, w = tid & 63;  // t = s*64 + w
        const float* p = out + (size_t)(1008 + s) * TSTRIDE + (size_t)b * 16384
                             + (size_t)j * 128 + (size_t)w * 2;
        sbu[s * 64 + w] = *(const float2*)p;
    }

    // lambda_bar for this k
    float delta = delta_p[0];
    float ar = lre[k], ai = lim[k];
    float e = expf(ar * delta);
    float s_, co;
    sincosf(ai * delta, &s_, &co);
    float lbr = e * co, lbi = e * s_;
    __syncthreads();

    // per-chunk partial
    {
        float pr = 0.0f, pi = 0.0f;
        int t0 = c * TC;
        for (int s2 = 0; s2 < TC; ++s2) {
            float2 bu = sbu[t0 + s2];
            float nr2 = lbr * pr - lbi * pi + bu.x;
            float ni2 = lbr * pi + lbi * pr + bu.y;
            pr = nr2; pi = ni2;
        }
        sP[c][k] = make_float2(pr, pi);
    }
    __syncthreads();

    // chunk-boundary combine on 128 threads: G = lambda^128
    if (tid < H_DIM) {
        float gr = lbr, gi = lbi;
#pragma unroll
        for (int q = 0; q < 7; ++q) {
            float tr = gr * gr - gi * gi;
            float ti = 2.0f * gr * gi;
            gr = tr; gi = ti;
        }
        float xr = 0.0f, xi = 0.0f;
#pragma unroll
        for (int cc = 0; cc < NC; ++cc) {
            sX[cc][tid] = make_float2(xr, xi);
            float2 p = sP[cc][tid];
            float nr2 = gr * xr - gi * xi + p.x;
            float ni2 = gr * xi + gi * xr + p.y;
            xr = nr2; xi = ni2;
        }
    }
    __syncthreads();

    // final scan within chunk; store REAL part only (nontemporal)
    {
        float2 x0 = sX[c][k];
        float xr = x0.x, xi = x0.y;
        int t0 = c * TC;
        float* outr = out + ((size_t)b * H_DIM + j) * H_DIM + k + (size_t)t0 * TSTRIDE;
        for (int s2 = 0; s2 < TC; ++s2) {
            float2 bu = sbu[t0 + s2];
            float nr2 = lbr * xr - lbi * xi + bu.x;
            float ni2 = lbr * xi + lbi * xr + bu.y;
            xr = nr2; xi = ni2;
            __builtin_nontemporal_store(xr, outr + (size_t)s2 * TSTRIDE);
        }
    }
}

// ---------------------------------------------------------------------------
extern "C" void kernel_launch(void* const* d_in, const int* in_sizes, int n_in,
                              void* d_out, int out_size, void* d_ws, size_t ws_size,
                              hipStream_t stream) {
    const float* u      = (const float*)d_in[0];
    const float* delta  = (const float*)d_in[1];
    const float* lre    = (const float*)d_in[2];
    const float* lim    = (const float*)d_in[3];
    const float* b_re   = (const float*)d_in[4];
    const float* b_im   = (const float*)d_in[5];
    float* out = (float*)d_out;

    if ((size_t)out_size >= PLANE) {
        bu_kernel<<<BATCH * 128, 1024, 0, stream>>>(u, delta, lre, lim, b_re, b_im, out);
        scan_kernel<<<BATCH * H_DIM, 1024, 0, stream>>>(delta, lre, lim, out);
    }
}